// Round 1
// baseline (616.891 us; speedup 1.0000x reference)
//
#include <hip/hip_runtime.h>
#include <hip/hip_bf16.h>
#include <math.h>

#define BB   16
#define NN   96
#define DD   128
#define NCLS 10

__device__ __forceinline__ float scalar_as_float(int v) {
    // python scalar may arrive as int32 or as float32 bit pattern
    if (v >= -1000000 && v <= 1000000) return (float)v;
    return __int_as_float(v);
}

// ---------------- init: e = embed_W[tok]; x = e; e_proj = e @ W1e ----------------
__global__ __launch_bounds__(128) void k_init(
    const int* __restrict__ tok, const float* __restrict__ embed_W,
    const float* __restrict__ W1, float* __restrict__ x, float* __restrict__ e_proj)
{
    const int row = blockIdx.y * NN + blockIdx.x;
    const int t = threadIdx.x;
    __shared__ float e_s[DD];
    const int tk = tok[row];
    const float ev = embed_W[tk * DD + t];
    e_s[t] = ev;
    x[row * DD + t] = ev;
    __syncthreads();
    float acc = 0.f;
#pragma unroll 8
    for (int k = 0; k < DD; ++k) acc = fmaf(e_s[k], W1[k * DD + t], acc);
    e_proj[row * DD + t] = acc;
}

// ---------------- per round: xj_proj = x @ W1x ----------------
__global__ __launch_bounds__(128) void k_xproj(
    const float* __restrict__ x, const float* __restrict__ W1x, float* __restrict__ xj)
{
    const int row = blockIdx.y * NN + blockIdx.x;
    const int t = threadIdx.x;
    __shared__ float xs[DD];
    xs[t] = x[row * DD + t];
    __syncthreads();
    float acc = 0.f;
#pragma unroll 8
    for (int k = 0; k < DD; ++k) acc = fmaf(xs[k], W1x[k * DD + t], acc);
    xj[row * DD + t] = acc;
}

// ---------------- per round heavy kernel: one block per (b,i) ----------------
// H(96x128) = relu(e_proj[b,i]+xj_proj[b,:]+b1); M = relu(H@W2+b2);
// agg[d] = sum_j A[b,j,i]*M[j][d]; x += agg; optional discretize (fused, row-local)
template<int DISC>
__global__ __launch_bounds__(256) void k_round(
    const float* __restrict__ Aab, const float* __restrict__ e_proj,
    const float* __restrict__ xj, const float* __restrict__ b1,
    const float* __restrict__ W2, const float* __restrict__ b2,
    const float* __restrict__ Wo1, const float* __restrict__ bo1,
    const float* __restrict__ Wo2, const float* __restrict__ embed_W,
    const int* __restrict__ tau_p, float* __restrict__ x)
{
    const int i = blockIdx.x;   // 0..95
    const int b = blockIdx.y;   // 0..15
    const int t = threadIdx.x;  // 0..255

    __shared__ __align__(16) float H_s[NN][DD + 4];  // pad: jg-broadcast reads hit distinct banks
    __shared__ __align__(16) float W2_s[DD][DD];
    __shared__ __align__(16) float v_s[DD];
    __shared__ __align__(16) float b2_s[DD];
    __shared__ __align__(16) float ac_s[NN];
    __shared__ __align__(16) float red_s[16][DD];
    __shared__ __align__(16) float xn_s[DD];
    __shared__ __align__(16) float hid_s[DD];
    __shared__ float lg_s[NCLS];
    __shared__ float p_s[NCLS];

    if (t < DD) { v_s[t] = e_proj[(b * NN + i) * DD + t] + b1[t]; b2_s[t] = b2[t]; }
    if (t < NN) ac_s[t] = Aab[(b * NN + t) * NN + i];  // A[b, j, i]
    {   // stage W2 (no dep on v_s)
        const float4* src = (const float4*)W2;
        float4* dst = (float4*)&W2_s[0][0];
        for (int idx = t; idx < DD * DD / 4; idx += 256) dst[idx] = src[idx];
    }
    __syncthreads();
    {   // stage xj tile with fused v-add + relu -> H_s (padded rows, 132 floats, 16B-aligned)
        const float4* src = (const float4*)(xj + b * NN * DD);
        for (int idx = t; idx < NN * DD / 4; idx += 256) {
            const int j  = idx >> 5;            // idx / 32
            const int k4 = (idx & 31) << 2;
            float4 u = src[idx];
            float4 v = ((const float4*)v_s)[idx & 31];
            float4 h;
            h.x = fmaxf(u.x + v.x, 0.f);
            h.y = fmaxf(u.y + v.y, 0.f);
            h.z = fmaxf(u.z + v.z, 0.f);
            h.w = fmaxf(u.w + v.w, 0.f);
            *(float4*)&H_s[j][k4] = h;
        }
    }
    __syncthreads();

    // GEMM: thread tile 6 rows (j) x 8 cols (d at d0..d0+3 and d0+64..d0+67)
    const int jg = t >> 4, dg = t & 15;
    const int j0 = jg * 6, d0 = dg * 4;
    float4 acc0[6], acc1[6];
#pragma unroll
    for (int jj = 0; jj < 6; ++jj) {
        acc0[jj] = make_float4(0.f, 0.f, 0.f, 0.f);
        acc1[jj] = make_float4(0.f, 0.f, 0.f, 0.f);
    }
#pragma unroll 4
    for (int k = 0; k < DD; ++k) {
        const float4 wa = *(const float4*)&W2_s[k][d0];
        const float4 wb = *(const float4*)&W2_s[k][d0 + 64];
#pragma unroll
        for (int jj = 0; jj < 6; ++jj) {
            const float h = H_s[j0 + jj][k];
            acc0[jj].x = fmaf(h, wa.x, acc0[jj].x);
            acc0[jj].y = fmaf(h, wa.y, acc0[jj].y);
            acc0[jj].z = fmaf(h, wa.z, acc0[jj].z);
            acc0[jj].w = fmaf(h, wa.w, acc0[jj].w);
            acc1[jj].x = fmaf(h, wb.x, acc1[jj].x);
            acc1[jj].y = fmaf(h, wb.y, acc1[jj].y);
            acc1[jj].z = fmaf(h, wb.z, acc1[jj].z);
            acc1[jj].w = fmaf(h, wb.w, acc1[jj].w);
        }
    }

    // m = relu(acc + b2); partial agg over this thread's 6 j rows
    const float4 bias0 = *(const float4*)&b2_s[d0];
    const float4 bias1 = *(const float4*)&b2_s[d0 + 64];
    float4 part0 = make_float4(0.f, 0.f, 0.f, 0.f);
    float4 part1 = make_float4(0.f, 0.f, 0.f, 0.f);
#pragma unroll
    for (int jj = 0; jj < 6; ++jj) {
        const float a = ac_s[j0 + jj];
        part0.x = fmaf(a, fmaxf(acc0[jj].x + bias0.x, 0.f), part0.x);
        part0.y = fmaf(a, fmaxf(acc0[jj].y + bias0.y, 0.f), part0.y);
        part0.z = fmaf(a, fmaxf(acc0[jj].z + bias0.z, 0.f), part0.z);
        part0.w = fmaf(a, fmaxf(acc0[jj].w + bias0.w, 0.f), part0.w);
        part1.x = fmaf(a, fmaxf(acc1[jj].x + bias1.x, 0.f), part1.x);
        part1.y = fmaf(a, fmaxf(acc1[jj].y + bias1.y, 0.f), part1.y);
        part1.z = fmaf(a, fmaxf(acc1[jj].z + bias1.z, 0.f), part1.z);
        part1.w = fmaf(a, fmaxf(acc1[jj].w + bias1.w, 0.f), part1.w);
    }
    *(float4*)&red_s[jg][d0]      = part0;
    *(float4*)&red_s[jg][d0 + 64] = part1;
    __syncthreads();

    float xn = 0.f;
    if (t < DD) {
        float aggv = 0.f;
#pragma unroll
        for (int g = 0; g < 16; ++g) aggv += red_s[g][t];
        xn = x[(b * NN + i) * DD + t] + aggv;
        xn_s[t] = xn;
    }
    __syncthreads();

    if (DISC) {
        if (t < DD) {
            float hsum = bo1[t];
#pragma unroll 8
            for (int k = 0; k < DD; ++k) hsum = fmaf(xn_s[k], Wo1[k * DD + t], hsum);
            hid_s[t] = fmaxf(hsum, 0.f);
        }
        __syncthreads();
        if (t < NCLS) {
            float l = 0.f;
#pragma unroll 8
            for (int k = 0; k < DD; ++k) l = fmaf(hid_s[k], Wo2[k * NCLS + t], l);
            lg_s[t] = l;
        }
        __syncthreads();
        if (t == 0) {
            const float inv_tau = 1.f / scalar_as_float(tau_p[0]);
            float mx = lg_s[0];
#pragma unroll
            for (int c = 1; c < NCLS; ++c) mx = fmaxf(mx, lg_s[c]);
            float e[NCLS];
            float den = 0.f;
#pragma unroll
            for (int c = 0; c < NCLS; ++c) { e[c] = expf((lg_s[c] - mx) * inv_tau); den += e[c]; }
            const float invden = 1.f / den;
#pragma unroll
            for (int c = 0; c < NCLS; ++c) p_s[c] = e[c] * invden;
        }
        __syncthreads();
        if (t < DD) {
            float add = 0.f;
#pragma unroll
            for (int c = 0; c < NCLS; ++c) add = fmaf(p_s[c], embed_W[(4 + c) * DD + t], add);
            xn += add;
        }
    }
    if (t < DD) x[(b * NN + i) * DD + t] = xn;
}

// ---------------- final heads: x_all = head(x); out = x_all[:,0,:] ----------------
__global__ __launch_bounds__(128) void k_head(
    const float* __restrict__ x, const float* __restrict__ Wo1,
    const float* __restrict__ bo1, const float* __restrict__ Wo2,
    float* __restrict__ out, float* __restrict__ x_all)
{
    const int n = blockIdx.x, b = blockIdx.y;
    const int row = b * NN + n;
    const int t = threadIdx.x;
    __shared__ float xs[DD], hid[DD];
    xs[t] = x[row * DD + t];
    __syncthreads();
    float hsum = bo1[t];
#pragma unroll 8
    for (int k = 0; k < DD; ++k) hsum = fmaf(xs[k], Wo1[k * DD + t], hsum);
    hid[t] = fmaxf(hsum, 0.f);
    __syncthreads();
    if (t < NCLS) {
        float l = 0.f;
#pragma unroll 8
        for (int k = 0; k < DD; ++k) l = fmaf(hid[k], Wo2[k * NCLS + t], l);
        x_all[row * NCLS + t] = l;
        if (n == 0) out[b * NCLS + t] = l;
    }
}

extern "C" void kernel_launch(void* const* d_in, const int* in_sizes, int n_in,
                              void* d_out, int out_size, void* d_ws, size_t ws_size,
                              hipStream_t stream)
{
    (void)in_sizes; (void)n_in; (void)out_size; (void)ws_size;
    const int*   tok     = (const int*)d_in[0];
    const float* Aab     = (const float*)d_in[1];
    const float* embed_W = (const float*)d_in[2];
    const float* W1      = (const float*)d_in[3];
    const float* b1      = (const float*)d_in[4];
    const float* W2      = (const float*)d_in[5];
    const float* b2      = (const float*)d_in[6];
    const float* Wo1     = (const float*)d_in[7];
    const float* bo1     = (const float*)d_in[8];
    const float* Wo2     = (const float*)d_in[9];
    const int*   tau_p   = (const int*)d_in[11];

    float* out   = (float*)d_out;
    float* x_all = out + BB * NCLS;

    float* ws     = (float*)d_ws;
    float* x      = ws;
    float* e_proj = ws + BB * NN * DD;
    float* xjp    = ws + 2 * BB * NN * DD;

    dim3 grid(NN, BB);
    k_init<<<grid, 128, 0, stream>>>(tok, embed_W, W1, x, e_proj);
    for (int r = 0; r < 5; ++r) {
        k_xproj<<<grid, 128, 0, stream>>>(x, W1 + DD * DD, xjp);
        if (r < 4)
            k_round<1><<<grid, 256, 0, stream>>>(Aab, e_proj, xjp, b1, W2, b2,
                                                 Wo1, bo1, Wo2, embed_W, tau_p, x);
        else
            k_round<0><<<grid, 256, 0, stream>>>(Aab, e_proj, xjp, b1, W2, b2,
                                                 Wo1, bo1, Wo2, embed_W, tau_p, x);
    }
    k_head<<<grid, 128, 0, stream>>>(x, Wo1, bo1, Wo2, out, x_all);
}

// Round 2
// 178.828 us; speedup vs baseline: 3.4496x; 3.4496x over previous
//
#include <hip/hip_runtime.h>
#include <hip/hip_bf16.h>
#include <math.h>

#define BB   16
#define NN   96
#define DD   128
#define NCLS 10

typedef __attribute__((ext_vector_type(8))) short bf16x8;
typedef __attribute__((ext_vector_type(4))) float f32x4;

__device__ __forceinline__ float scalar_as_float(int v) {
    if (v >= -1000000 && v <= 1000000) return (float)v;
    return __int_as_float(v);
}

// round-to-nearest-even f32 -> bf16 bits
__device__ __forceinline__ unsigned short f2bf(float f) {
    unsigned u = __float_as_uint(f);
    unsigned r = (u + 0x7FFFu + ((u >> 16) & 1u)) >> 16;
    return (unsigned short)r;
}
__device__ __forceinline__ float bf2f(unsigned short h) {
    return __uint_as_float(((unsigned)h) << 16);
}

// ---------------- one-time: pack W2 into MFMA B-fragments, bf16 hi + lo ----------------
// frag-major layout: [dtile 0..7][kchunk 0..3][lane 0..63][e 0..7]
// B-frag mapping (16x16x32): lane l holds B[k = kc*32 + (l>>4)*8 + e][col = dt*16 + (l&15)]
__global__ __launch_bounds__(256) void k_w2prep(
    const float* __restrict__ W2, unsigned short* __restrict__ whi,
    unsigned short* __restrict__ wlo)
{
    const int dt = blockIdx.x;        // 0..7
    const int kc = threadIdx.x >> 6;  // 0..3
    const int l  = threadIdx.x & 63;
    const int base = ((dt * 4 + kc) * 64 + l) * 8;
    const int c = dt * 16 + (l & 15);
#pragma unroll
    for (int e = 0; e < 8; ++e) {
        const int k = kc * 32 + (l >> 4) * 8 + e;
        const float wv = W2[k * DD + c];
        const unsigned short h = f2bf(wv);
        whi[base + e] = h;
        wlo[base + e] = f2bf(wv - bf2f(h));
    }
}

// ---------------- init: e = embed_W[tok]; x = e; e_proj = e @ W1e ----------------
__global__ __launch_bounds__(128) void k_init(
    const int* __restrict__ tok, const float* __restrict__ embed_W,
    const float* __restrict__ W1, float* __restrict__ x, float* __restrict__ e_proj)
{
    const int row = blockIdx.y * NN + blockIdx.x;
    const int t = threadIdx.x;
    __shared__ float e_s[DD];
    const int tk = tok[row];
    const float ev = embed_W[tk * DD + t];
    e_s[t] = ev;
    x[row * DD + t] = ev;
    __syncthreads();
    float acc = 0.f;
#pragma unroll 8
    for (int k = 0; k < DD; ++k) acc = fmaf(e_s[k], W1[k * DD + t], acc);
    e_proj[row * DD + t] = acc;
}

// ---------------- per round: xj_proj = x @ W1x ----------------
__global__ __launch_bounds__(128) void k_xproj(
    const float* __restrict__ x, const float* __restrict__ W1x, float* __restrict__ xj)
{
    const int row = blockIdx.y * NN + blockIdx.x;
    const int t = threadIdx.x;
    __shared__ float xs[DD];
    xs[t] = x[row * DD + t];
    __syncthreads();
    float acc = 0.f;
#pragma unroll 8
    for (int k = 0; k < DD; ++k) acc = fmaf(xs[k], W1x[k * DD + t], acc);
    xj[row * DD + t] = acc;
}

#define MFMA(A, B, C) __builtin_amdgcn_mfma_f32_16x16x32_bf16(A, B, C, 0, 0, 0)

// ---------------- per round heavy kernel: one block per (b,i), MFMA GEMM ----------------
template<int DISC>
__global__ __launch_bounds__(256, 3) void k_round(
    const float* __restrict__ Aab, const float* __restrict__ e_proj,
    const float* __restrict__ xj, const float* __restrict__ b1,
    const unsigned short* __restrict__ w2hi, const unsigned short* __restrict__ w2lo,
    const float* __restrict__ b2,
    const float* __restrict__ Wo1, const float* __restrict__ bo1,
    const float* __restrict__ Wo2, const float* __restrict__ embed_W,
    const int* __restrict__ tau_p, float* __restrict__ x)
{
    const int i = blockIdx.x;   // 0..95
    const int b = blockIdx.y;   // 0..15
    const int t = threadIdx.x;  // 0..255
    const int w = t >> 6;       // wave 0..3, owns col-tiles w and w+4
    const int l = t & 63;

    __shared__ unsigned short hs[NN][DD + 8];  // bf16 H, row stride 136 (17x16B: ~2-way banks)
    __shared__ float v_s[DD];
    __shared__ float ac_s[NN];
    __shared__ float agg_s[DD];
    __shared__ float xn_s[DD];
    __shared__ float hid_s[DD];
    __shared__ float lg_s[NCLS], p_s[NCLS];

    if (t < DD) v_s[t] = e_proj[(b * NN + i) * DD + t] + b1[t];
    if (t < NN) ac_s[t] = Aab[(b * NN + t) * NN + i];  // A[b, j, i]

    // B-fragments: registers, straight from global (L2-resident, frag-major = coalesced)
    const bf16x8* WH = (const bf16x8*)w2hi;
    const bf16x8* WL = (const bf16x8*)w2lo;
    bf16x8 bh[2][4], bl[2][4];
#pragma unroll
    for (int dti = 0; dti < 2; ++dti) {
        const int dt = w + dti * 4;
#pragma unroll
        for (int kc = 0; kc < 4; ++kc) {
            bh[dti][kc] = WH[(dt * 4 + kc) * 64 + l];
            bl[dti][kc] = WL[(dt * 4 + kc) * 64 + l];
        }
    }
    const float b2v0 = b2[w * 16 + (l & 15)];
    const float b2v1 = b2[64 + w * 16 + (l & 15)];

    __syncthreads();

    {   // H = relu(v + xj) -> bf16 LDS
        const float4* src = (const float4*)(xj + b * NN * DD);
        const float4* vv  = (const float4*)v_s;
#pragma unroll
        for (int it = 0; it < 12; ++it) {
            const int idx = t + it * 256;        // 0..3071
            const int j = idx >> 5, k4 = (idx & 31) << 2;
            const float4 u = src[idx];
            const float4 v = vv[idx & 31];
            ushort4 hh;
            hh.x = f2bf(fmaxf(u.x + v.x, 0.f));
            hh.y = f2bf(fmaxf(u.y + v.y, 0.f));
            hh.z = f2bf(fmaxf(u.z + v.z, 0.f));
            hh.w = f2bf(fmaxf(u.w + v.w, 0.f));
            *(ushort4*)&hs[j][k4] = hh;
        }
    }
    __syncthreads();

    // GEMM: each wave sweeps all six 16-row j-tiles for its two 16-col d-tiles
    float aggp0 = 0.f, aggp1 = 0.f;
#pragma unroll
    for (int jt = 0; jt < 6; ++jt) {
        const unsigned short* hrow = &hs[jt * 16 + (l & 15)][(l >> 4) * 8];
        const bf16x8 a0 = *(const bf16x8*)(hrow);
        const bf16x8 a1 = *(const bf16x8*)(hrow + 32);
        const bf16x8 a2 = *(const bf16x8*)(hrow + 64);
        const bf16x8 a3 = *(const bf16x8*)(hrow + 96);
        f32x4 c0a = {0.f, 0.f, 0.f, 0.f}, c0b = {0.f, 0.f, 0.f, 0.f};
        f32x4 c1a = {0.f, 0.f, 0.f, 0.f}, c1b = {0.f, 0.f, 0.f, 0.f};
        c0a = MFMA(a0, bh[0][0], c0a);  c0b = MFMA(a0, bl[0][0], c0b);
        c1a = MFMA(a0, bh[1][0], c1a);  c1b = MFMA(a0, bl[1][0], c1b);
        c0a = MFMA(a1, bh[0][1], c0a);  c0b = MFMA(a1, bl[0][1], c0b);
        c1a = MFMA(a1, bh[1][1], c1a);  c1b = MFMA(a1, bl[1][1], c1b);
        c0a = MFMA(a2, bh[0][2], c0a);  c0b = MFMA(a2, bl[0][2], c0b);
        c1a = MFMA(a2, bh[1][2], c1a);  c1b = MFMA(a2, bl[1][2], c1b);
        c0a = MFMA(a3, bh[0][3], c0a);  c0b = MFMA(a3, bl[0][3], c0b);
        c1a = MFMA(a3, bh[1][3], c1a);  c1b = MFMA(a3, bl[1][3], c1b);
        const f32x4 m0 = c0a + c0b;
        const f32x4 m1 = c1a + c1b;
        // C-frag: col = l&15 (fixed per lane), row j = jt*16 + (l>>4)*4 + r
#pragma unroll
        for (int r = 0; r < 4; ++r) {
            const float a = ac_s[jt * 16 + (l >> 4) * 4 + r];
            aggp0 = fmaf(a, fmaxf(m0[r] + b2v0, 0.f), aggp0);
            aggp1 = fmaf(a, fmaxf(m1[r] + b2v1, 0.f), aggp1);
        }
    }
    aggp0 += __shfl_xor(aggp0, 16); aggp0 += __shfl_xor(aggp0, 32);
    aggp1 += __shfl_xor(aggp1, 16); aggp1 += __shfl_xor(aggp1, 32);
    if (l < 16) {
        agg_s[w * 16 + l]      = aggp0;
        agg_s[64 + w * 16 + l] = aggp1;
    }
    __syncthreads();

    float xn = 0.f;
    if (t < DD) {
        xn = x[(b * NN + i) * DD + t] + agg_s[t];
        xn_s[t] = xn;
    }
    __syncthreads();

    if (DISC) {
        if (t < DD) {
            float hsum = bo1[t];
#pragma unroll 8
            for (int k = 0; k < DD; ++k) hsum = fmaf(xn_s[k], Wo1[k * DD + t], hsum);
            hid_s[t] = fmaxf(hsum, 0.f);
        }
        __syncthreads();
        if (t < NCLS) {
            float lg = 0.f;
#pragma unroll 8
            for (int k = 0; k < DD; ++k) lg = fmaf(hid_s[k], Wo2[k * NCLS + t], lg);
            lg_s[t] = lg;
        }
        __syncthreads();
        if (t == 0) {
            const float inv_tau = 1.f / scalar_as_float(tau_p[0]);
            float mx = lg_s[0];
#pragma unroll
            for (int c = 1; c < NCLS; ++c) mx = fmaxf(mx, lg_s[c]);
            float e[NCLS];
            float den = 0.f;
#pragma unroll
            for (int c = 0; c < NCLS; ++c) { e[c] = expf((lg_s[c] - mx) * inv_tau); den += e[c]; }
            const float invden = 1.f / den;
#pragma unroll
            for (int c = 0; c < NCLS; ++c) p_s[c] = e[c] * invden;
        }
        __syncthreads();
        if (t < DD) {
            float add = 0.f;
#pragma unroll
            for (int c = 0; c < NCLS; ++c) add = fmaf(p_s[c], embed_W[(4 + c) * DD + t], add);
            xn += add;
        }
    }
    if (t < DD) x[(b * NN + i) * DD + t] = xn;
}

// ---------------- final heads ----------------
__global__ __launch_bounds__(128) void k_head(
    const float* __restrict__ x, const float* __restrict__ Wo1,
    const float* __restrict__ bo1, const float* __restrict__ Wo2,
    float* __restrict__ out, float* __restrict__ x_all)
{
    const int n = blockIdx.x, b = blockIdx.y;
    const int row = b * NN + n;
    const int t = threadIdx.x;
    __shared__ float xs[DD], hid[DD];
    xs[t] = x[row * DD + t];
    __syncthreads();
    float hsum = bo1[t];
#pragma unroll 8
    for (int k = 0; k < DD; ++k) hsum = fmaf(xs[k], Wo1[k * DD + t], hsum);
    hid[t] = fmaxf(hsum, 0.f);
    __syncthreads();
    if (t < NCLS) {
        float lg = 0.f;
#pragma unroll 8
        for (int k = 0; k < DD; ++k) lg = fmaf(hid[k], Wo2[k * NCLS + t], lg);
        x_all[row * NCLS + t] = lg;
        if (n == 0) out[b * NCLS + t] = lg;
    }
}

extern "C" void kernel_launch(void* const* d_in, const int* in_sizes, int n_in,
                              void* d_out, int out_size, void* d_ws, size_t ws_size,
                              hipStream_t stream)
{
    (void)in_sizes; (void)n_in; (void)out_size; (void)ws_size;
    const int*   tok     = (const int*)d_in[0];
    const float* Aab     = (const float*)d_in[1];
    const float* embed_W = (const float*)d_in[2];
    const float* W1      = (const float*)d_in[3];
    const float* b1      = (const float*)d_in[4];
    const float* W2      = (const float*)d_in[5];
    const float* b2      = (const float*)d_in[6];
    const float* Wo1     = (const float*)d_in[7];
    const float* bo1     = (const float*)d_in[8];
    const float* Wo2     = (const float*)d_in[9];
    const int*   tau_p   = (const int*)d_in[11];

    float* out   = (float*)d_out;
    float* x_all = out + BB * NCLS;

    float* ws     = (float*)d_ws;
    float* x      = ws;
    float* e_proj = ws + BB * NN * DD;
    float* xjp    = ws + 2 * BB * NN * DD;
    unsigned short* w2hi = (unsigned short*)(ws + 3 * BB * NN * DD);
    unsigned short* w2lo = w2hi + DD * DD;

    dim3 grid(NN, BB);
    k_w2prep<<<8, 256, 0, stream>>>(W2, w2hi, w2lo);
    k_init<<<grid, 128, 0, stream>>>(tok, embed_W, W1, x, e_proj);
    for (int r = 0; r < 5; ++r) {
        k_xproj<<<grid, 128, 0, stream>>>(x, W1 + DD * DD, xjp);
        if (r < 4)
            k_round<1><<<grid, 256, 0, stream>>>(Aab, e_proj, xjp, b1, w2hi, w2lo, b2,
                                                 Wo1, bo1, Wo2, embed_W, tau_p, x);
        else
            k_round<0><<<grid, 256, 0, stream>>>(Aab, e_proj, xjp, b1, w2hi, w2lo, b2,
                                                 Wo1, bo1, Wo2, embed_W, tau_p, x);
    }
    k_head<<<grid, 128, 0, stream>>>(x, Wo1, bo1, Wo2, out, x_all);
}

// Round 3
// 137.609 us; speedup vs baseline: 4.4829x; 1.2995x over previous
//
#include <hip/hip_runtime.h>
#include <hip/hip_bf16.h>
#include <math.h>

#define BB   16
#define NN   96
#define DD   128
#define NCLS 10

typedef __attribute__((ext_vector_type(8))) short bf16x8;
typedef __attribute__((ext_vector_type(4))) float f32x4;

__device__ __forceinline__ float scalar_as_float(int v) {
    if (v >= -1000000 && v <= 1000000) return (float)v;
    return __int_as_float(v);
}
__device__ __forceinline__ unsigned short f2bf(float f) {
    unsigned u = __float_as_uint(f);
    return (unsigned short)((u + 0x7FFFu + ((u >> 16) & 1u)) >> 16);
}
__device__ __forceinline__ float bf2f(unsigned short h) {
    return __uint_as_float(((unsigned)h) << 16);
}

// ---------------- one-time: pack W2 into MFMA B-fragments, bf16 hi + lo ----------------
// frag-major: [dtile 0..7][kchunk 0..3][lane 0..63][e 0..7]
// B-frag (16x16x32): lane l holds B[k = kc*32 + (l>>4)*8 + e][col = dt*16 + (l&15)]
__global__ __launch_bounds__(256) void k_w2prep(
    const float* __restrict__ W2, unsigned short* __restrict__ whi,
    unsigned short* __restrict__ wlo)
{
    const int dt = blockIdx.x;
    const int kc = threadIdx.x >> 6;
    const int l  = threadIdx.x & 63;
    const int base = ((dt * 4 + kc) * 64 + l) * 8;
    const int c = dt * 16 + (l & 15);
#pragma unroll
    for (int e = 0; e < 8; ++e) {
        const int k = kc * 32 + (l >> 4) * 8 + e;
        const float wv = W2[k * DD + c];
        const unsigned short h = f2bf(wv);
        whi[base + e] = h;
        wlo[base + e] = f2bf(wv - bf2f(h));
    }
}

// ---------------- one-time: AT[b][i][j] = A[b][j][i] (coalesce k_round's A reads) ----------
__global__ __launch_bounds__(256) void k_atrans(
    const float* __restrict__ A, float* __restrict__ AT)
{
    const int b = blockIdx.x;
    __shared__ float tile[NN][NN + 1];
    for (int idx = threadIdx.x; idx < NN * NN; idx += 256)
        tile[idx / NN][idx % NN] = A[b * NN * NN + idx];
    __syncthreads();
    for (int idx = threadIdx.x; idx < NN * NN; idx += 256) {
        const int i = idx / NN, j = idx % NN;
        AT[b * NN * NN + idx] = tile[j][i];
    }
}

// ---------------- init: x = e = embed_W[tok]; e_proj = e@W1e; xj = e@W1x ----------------
__global__ __launch_bounds__(128) void k_init(
    const int* __restrict__ tok, const float* __restrict__ embed_W,
    const float* __restrict__ W1, float* __restrict__ x,
    float* __restrict__ e_proj, float* __restrict__ xj)
{
    const int row = blockIdx.y * NN + blockIdx.x;
    const int t = threadIdx.x;
    __shared__ float e_s[DD];
    const float ev = embed_W[tok[row] * DD + t];
    e_s[t] = ev;
    x[row * DD + t] = ev;
    __syncthreads();
    float a1 = 0.f, a2 = 0.f;
#pragma unroll 8
    for (int k = 0; k < DD; ++k) {
        const float e = e_s[k];
        a1 = fmaf(e, W1[k * DD + t], a1);
        a2 = fmaf(e, W1[(DD + k) * DD + t], a2);
    }
    e_proj[row * DD + t] = a1;
    xj[row * DD + t]     = a2;
}

#define MFMA(A, B, C) __builtin_amdgcn_mfma_f32_16x16x32_bf16(A, B, C, 0, 0, 0)

// ---------------- per round heavy kernel: block=(b,i), 8 waves, wave w owns d-tile w ------
__global__ __launch_bounds__(512, 6) void k_round(
    const float* __restrict__ AT, const float* __restrict__ e_proj,
    const float* __restrict__ xj, const float* __restrict__ b1,
    const unsigned short* __restrict__ w2hi, const unsigned short* __restrict__ w2lo,
    const float* __restrict__ b2, float* __restrict__ x)
{
    const int i = blockIdx.x;
    const int b = blockIdx.y;
    const int t = threadIdx.x;   // 0..511
    const int w = t >> 6;        // wave = d-tile 0..7
    const int l = t & 63;

    __shared__ __align__(16) unsigned short hs[NN * DD];  // XOR-swizzled bf16 H
    __shared__ float v_s[DD];
    __shared__ float ac_s[NN];
    __shared__ float agg_s[DD];

    if (t < DD) v_s[t] = e_proj[(b * NN + i) * DD + t] + b1[t];
    else if (t < DD + NN) ac_s[t - DD] = AT[(b * NN + i) * NN + (t - DD)];

    // B-fragments for this wave's d-tile: hi + lo, straight from L2 (frag-major)
    const bf16x8* WH = (const bf16x8*)w2hi;
    const bf16x8* WL = (const bf16x8*)w2lo;
    bf16x8 bh[4], bl[4];
#pragma unroll
    for (int kc = 0; kc < 4; ++kc) {
        bh[kc] = WH[(w * 4 + kc) * 64 + l];
        bl[kc] = WL[(w * 4 + kc) * 64 + l];
    }
    const float b2v = b2[w * 16 + (l & 15)];
    __syncthreads();

    {   // H = relu(v + xj) -> bf16 LDS, swizzled: short_idx ^ ((row&7)<<3)
        const float4* src = (const float4*)(xj + b * NN * DD);
        const float4* vv  = (const float4*)v_s;
#pragma unroll
        for (int it = 0; it < 6; ++it) {
            const int idx = t + it * 512;          // 0..3071
            const int j = idx >> 5, k4 = (idx & 31) << 2;
            const float4 u = src[idx];
            const float4 v = vv[idx & 31];
            ushort4 hh;
            hh.x = f2bf(fmaxf(u.x + v.x, 0.f));
            hh.y = f2bf(fmaxf(u.y + v.y, 0.f));
            hh.z = f2bf(fmaxf(u.z + v.z, 0.f));
            hh.w = f2bf(fmaxf(u.w + v.w, 0.f));
            *(ushort4*)&hs[(j * DD + k4) ^ ((j & 7) << 3)] = hh;
        }
    }
    __syncthreads();

    // GEMM: wave sweeps six 16-row j-tiles for its one 16-col d-tile (hi+lo MFMA)
    float aggp = 0.f;
#pragma unroll
    for (int jt = 0; jt < 6; ++jt) {
        const int row = jt * 16 + (l & 15);
        const int ko  = (l >> 4) * 8;
        const int sw  = (row & 7) << 3;
        const bf16x8 a0 = *(const bf16x8*)&hs[(row * DD + ko     ) ^ sw];
        const bf16x8 a1 = *(const bf16x8*)&hs[(row * DD + ko + 32) ^ sw];
        const bf16x8 a2 = *(const bf16x8*)&hs[(row * DD + ko + 64) ^ sw];
        const bf16x8 a3 = *(const bf16x8*)&hs[(row * DD + ko + 96) ^ sw];
        f32x4 ch = {0.f, 0.f, 0.f, 0.f}, cl = {0.f, 0.f, 0.f, 0.f};
        ch = MFMA(a0, bh[0], ch);  cl = MFMA(a0, bl[0], cl);
        ch = MFMA(a1, bh[1], ch);  cl = MFMA(a1, bl[1], cl);
        ch = MFMA(a2, bh[2], ch);  cl = MFMA(a2, bl[2], cl);
        ch = MFMA(a3, bh[3], ch);  cl = MFMA(a3, bl[3], cl);
        const f32x4 m = ch + cl;
        // C-frag: col = l&15, row j = jt*16 + (l>>4)*4 + r
#pragma unroll
        for (int r = 0; r < 4; ++r) {
            const float a = ac_s[jt * 16 + (l >> 4) * 4 + r];
            aggp = fmaf(a, fmaxf(m[r] + b2v, 0.f), aggp);
        }
    }
    aggp += __shfl_xor(aggp, 16);
    aggp += __shfl_xor(aggp, 32);
    if (l < 16) agg_s[w * 16 + l] = aggp;
    __syncthreads();

    if (t < DD) x[(b * NN + i) * DD + t] += agg_s[t];
}

// ---------------- batched discretize (FINAL=0) / final head (FINAL=1) ----------------
// 2 rows per 256-thread block; logits via per-lane partials + shfl butterfly.
template<int FINAL>
__global__ __launch_bounds__(256) void k_disc(
    const float* __restrict__ Wo1, const float* __restrict__ bo1,
    const float* __restrict__ Wo2, const float* __restrict__ embed_W,
    const float* __restrict__ W1x, const int* __restrict__ tau_p,
    float* __restrict__ x, float* __restrict__ xj,
    float* __restrict__ out, float* __restrict__ x_all)
{
    const int t  = threadIdx.x;
    const int rr = t >> 7;          // row within block
    const int h  = t & 127;         // feature
    const int ww = t >> 6;          // wave 0..3
    const int l  = t & 63;
    const int row = blockIdx.x * 2 + rr;

    __shared__ float xs[2][DD];
    __shared__ float wred[4][NCLS];

    xs[rr][h] = x[row * DD + h];
    __syncthreads();

    // hid[h] = relu(bo1 + x·Wo1[:,h])  (Wo1 reads coalesced, L2-hot)
    float hv = bo1[h];
#pragma unroll 8
    for (int k = 0; k < DD; ++k) hv = fmaf(xs[rr][k], Wo1[k * DD + h], hv);
    hv = fmaxf(hv, 0.f);

    // logits: per-lane partials (k = h), butterfly reduce within wave
    float lgp[NCLS];
#pragma unroll
    for (int c = 0; c < NCLS; ++c) lgp[c] = hv * Wo2[h * NCLS + c];
#pragma unroll
    for (int s = 1; s < 64; s <<= 1) {
#pragma unroll
        for (int c = 0; c < NCLS; ++c) lgp[c] += __shfl_xor(lgp[c], s);
    }
    if (l == 0) {
#pragma unroll
        for (int c = 0; c < NCLS; ++c) wred[ww][c] = lgp[c];
    }
    __syncthreads();

    if (FINAL) {
        if (h < NCLS) {
            const float lg = wred[2 * rr][h] + wred[2 * rr + 1][h];
            x_all[row * NCLS + h] = lg;
            if ((row % NN) == 0) out[(row / NN) * NCLS + h] = lg;
        }
        return;
    }

    // per-thread redundant softmax (no serialization)
    float lg[NCLS];
    float mx = -1e30f;
#pragma unroll
    for (int c = 0; c < NCLS; ++c) {
        lg[c] = wred[2 * rr][c] + wred[2 * rr + 1][c];
        mx = fmaxf(mx, lg[c]);
    }
    const float inv_tau = 1.f / scalar_as_float(tau_p[0]);
    float p[NCLS], den = 0.f;
#pragma unroll
    for (int c = 0; c < NCLS; ++c) { p[c] = expf((lg[c] - mx) * inv_tau); den += p[c]; }
    const float invden = 1.f / den;

    float xn = xs[rr][h];
#pragma unroll
    for (int c = 0; c < NCLS; ++c)
        xn = fmaf(p[c] * invden, embed_W[(4 + c) * DD + h], xn);
    x[row * DD + h] = xn;

    xs[rr][h] = xn;           // safe: every thread past the hid loop (wred barrier)
    __syncthreads();

    // next round's xj_proj = xn @ W1x (fused; replaces k_xproj)
    float xv = 0.f;
#pragma unroll 8
    for (int k = 0; k < DD; ++k) xv = fmaf(xs[rr][k], W1x[k * DD + h], xv);
    xj[row * DD + h] = xv;
}

extern "C" void kernel_launch(void* const* d_in, const int* in_sizes, int n_in,
                              void* d_out, int out_size, void* d_ws, size_t ws_size,
                              hipStream_t stream)
{
    (void)in_sizes; (void)n_in; (void)out_size; (void)ws_size;
    const int*   tok     = (const int*)d_in[0];
    const float* Aab     = (const float*)d_in[1];
    const float* embed_W = (const float*)d_in[2];
    const float* W1      = (const float*)d_in[3];
    const float* b1      = (const float*)d_in[4];
    const float* W2      = (const float*)d_in[5];
    const float* b2      = (const float*)d_in[6];
    const float* Wo1     = (const float*)d_in[7];
    const float* bo1     = (const float*)d_in[8];
    const float* Wo2     = (const float*)d_in[9];
    const int*   tau_p   = (const int*)d_in[11];

    float* out   = (float*)d_out;
    float* x_all = out + BB * NCLS;

    float* ws     = (float*)d_ws;
    float* x      = ws;                                   // 196608
    float* e_proj = ws + BB * NN * DD;                    // 196608
    float* xjp    = ws + 2 * BB * NN * DD;                // 196608
    float* ATr    = ws + 3 * BB * NN * DD;                // 147456
    unsigned short* w2hi = (unsigned short*)(ws + 3 * BB * NN * DD + BB * NN * NN);
    unsigned short* w2lo = w2hi + DD * DD;

    const float* W1x = W1 + DD * DD;

    dim3 grid(NN, BB);
    k_w2prep<<<8, 256, 0, stream>>>(W2, w2hi, w2lo);
    k_atrans<<<BB, 256, 0, stream>>>(Aab, ATr);
    k_init<<<grid, 128, 0, stream>>>(tok, embed_W, W1, x, e_proj, xjp);
    for (int r = 0; r < 5; ++r) {
        k_round<<<grid, 512, 0, stream>>>(ATr, e_proj, xjp, b1, w2hi, w2lo, b2, x);
        if (r < 4)
            k_disc<0><<<BB * NN / 2, 256, 0, stream>>>(Wo1, bo1, Wo2, embed_W, W1x,
                                                       tau_p, x, xjp, out, x_all);
    }
    k_disc<1><<<BB * NN / 2, 256, 0, stream>>>(Wo1, bo1, Wo2, embed_W, W1x,
                                               tau_p, x, xjp, out, x_all);
}